// Round 1
// baseline (387.444 us; speedup 1.0000x reference)
//
#include <hip/hip_runtime.h>
#include <math.h>

// Problem constants (from reference)
#define BATCHES 8192
#define D_IN    400
#define D_OUT   100
#define QD      10
#define TILE    50      // K-tile staged in LDS
#define ROWSP   51      // padded LDS row stride (51 mod 32 odd -> conflict-free)
#define NW      4       // waves (=batches) per block

// Full 64-lane butterfly reduction; every lane ends with the sum.
__device__ __forceinline__ float wsum64(float x) {
  #pragma unroll
  for (int m = 1; m < 64; m <<= 1) x += __shfl_xor(x, m, 64);
  return x;
}

// One wave handles one batch. Lane r owns rows r and r+64 of a 128-row
// zero-padded panel (rows 100..127 identically zero; their Q rows are never
// written). All QR reductions are in-wave shuffles -> no barriers in QR.
__global__ void frmap_qr_kernel(const float* __restrict__ X,
                                const float* __restrict__ W,
                                float* __restrict__ out) {
  __shared__ float smem[128 * ROWSP];   // W tile (rows padded to 128) / Q staging
  const int tid = threadIdx.x;
  const int r   = tid & 63;
  const int wv  = __builtin_amdgcn_readfirstlane(tid >> 6);  // uniform wave id
  const int b   = blockIdx.x * NW + wv;                      // uniform batch id
  const float* xb = X + (size_t)b * (D_IN * QD);             // uniform -> s_load

  // Zero LDS so rows 100..127 read as 0 in the GEMM.
  for (int idx = tid; idx < 128 * ROWSP; idx += 256) smem[idx] = 0.f;

  // ---------------- Phase 1: Y = W @ X[b], rows r and r+64 ----------------
  float acc0[QD], acc1[QD];
  #pragma unroll
  for (int q = 0; q < QD; ++q) { acc0[q] = 0.f; acc1[q] = 0.f; }

  for (int t = 0; t < D_IN / TILE; ++t) {
    const int i0 = t * TILE;
    __syncthreads();  // previous tile consumed (also covers the zero-init)
    for (int idx = tid; idx < D_OUT * TILE; idx += 256) {
      int o = idx / TILE;
      int c = idx - o * TILE;
      smem[o * ROWSP + c] = W[o * D_IN + i0 + c];
    }
    __syncthreads();
    #pragma unroll 5
    for (int ii = 0; ii < TILE; ++ii) {
      float w0 = smem[r * ROWSP + ii];          // lane stride 51 -> no conflicts
      float w1 = smem[(r + 64) * ROWSP + ii];   // rows >=100 read staged zeros
      const float* xr = xb + (size_t)(i0 + ii) * QD;
      #pragma unroll
      for (int q = 0; q < QD; ++q) {
        float xv = xr[q];                        // wave-uniform -> scalar load
        acc0[q] = fmaf(w0, xv, acc0[q]);
        acc1[q] = fmaf(w1, xv, acc1[q]);
      }
    }
  }
  __syncthreads();  // all waves finished reading W tiles; smem reusable

  // ---------------- Phase 2: Householder QR (LAPACK sgeqrf convention) ----
  // A is acc0 (row r) / acc1 (row r+64). v_j kept per lane, tau broadcast.
  float v0[QD], v1[QD], tau[QD];
  #pragma unroll
  for (int j = 0; j < QD; ++j) {
    // norm^2 of column j over rows j..127 (padding rows contribute 0)
    float cj0  = (r >= j) ? acc0[j] : 0.f;       // row r (r>=j includes alpha)
    float part = cj0 * cj0 + acc1[j] * acc1[j];  // row r+64 is always > j
    float sig  = wsum64(part);
    float alpha = __shfl(acc0[j], j, 64);        // A[j][j] lives on lane j
    float nrm  = sqrtf(sig);
    float beta = (alpha >= 0.f) ? -nrm : nrm;    // LAPACK sign convention
    float tj   = (nrm > 0.f) ? (beta - alpha) / beta : 0.f;
    float inv  = (nrm > 0.f) ? 1.f / (alpha - beta) : 0.f;  // no cancellation
    tau[j] = tj;
    v0[j]  = (r == j) ? 1.f : ((r > j) ? acc0[j] * inv : 0.f);
    v1[j]  = acc1[j] * inv;                      // zero on padding rows
    // apply H_j = I - tau v v^T to trailing columns
    #pragma unroll
    for (int k = j + 1; k < QD; ++k) {
      float p = v0[j] * acc0[k] + v1[j] * acc1[k];
      float s = wsum64(p) * tj;
      acc0[k] -= s * v0[j];
      acc1[k] -= s * v1[j];
    }
  }

  // ---------------- Phase 3: Q = H_0 ... H_9 * E (backward accumulation) --
  float q0[QD], q1[QD];
  #pragma unroll
  for (int c = 0; c < QD; ++c) { q0[c] = (r == c) ? 1.f : 0.f; q1[c] = 0.f; }
  #pragma unroll
  for (int j = QD - 1; j >= 0; --j) {
    #pragma unroll
    for (int c = j; c < QD; ++c) {   // columns < j are still e_c, untouched by H_j
      float p = v0[j] * q0[c] + v1[j] * q1[c];
      float s = wsum64(p) * tau[j];
      q0[c] -= s * v0[j];
      q1[c] -= s * v1[j];
    }
  }

  // ---------------- Phase 4: stage Q rows in LDS, store coalesced ---------
  float* stg = smem + wv * (D_OUT * QD);   // 1000 floats per wave, disjoint
  #pragma unroll
  for (int c = 0; c < QD; ++c) stg[r * QD + c] = q0[c];
  if (r < D_OUT - 64) {
    #pragma unroll
    for (int c = 0; c < QD; ++c) stg[(r + 64) * QD + c] = q1[c];
  }
  // same-wave LDS RAW: compiler inserts the lgkmcnt wait
  const float4* src = reinterpret_cast<const float4*>(stg);
  float4* dst = reinterpret_cast<float4*>(out + (size_t)b * (D_OUT * QD));
  #pragma unroll
  for (int u = r; u < (D_OUT * QD) / 4; u += 64) dst[u] = src[u];
}

extern "C" void kernel_launch(void* const* d_in, const int* in_sizes, int n_in,
                              void* d_out, int out_size, void* d_ws, size_t ws_size,
                              hipStream_t stream) {
  const float* X = (const float*)d_in[0];   // (8192, 400, 10) fp32
  const float* W = (const float*)d_in[1];   // (100, 400) fp32
  float* out = (float*)d_out;               // (8192, 100, 10) fp32
  dim3 grid(BATCHES / NW), block(256);
  hipLaunchKernelGGL(frmap_qr_kernel, grid, block, 0, stream, X, W, out);
}

// Round 2
// 323.941 us; speedup vs baseline: 1.1960x; 1.1960x over previous
//
#include <hip/hip_runtime.h>
#include <math.h>

#define BATCHES 8192
#define D_IN    400
#define D_OUT   100
#define QD      10

using bf16x8 = __attribute__((ext_vector_type(8))) short;
using f32x4  = __attribute__((ext_vector_type(4))) float;

// ===================== Kernel A: MFMA GEMM  Y[b] = W @ X[b] =====================
// bf16 3-split (wh*xh + wl*xh + wh*xl), 16x16x32 MFMA.
// Block = 256 (4 waves); each wave owns 2 batches -> 8 batches/block.
// K tiled by 64 (7 tiles, zero-padded past k=400). LDS holds W tile (hi/lo) in
// exact fragment order + per-wave X tiles (hi/lo) in exact fragment order, so
// every frag load is one ds_read_b128 at (tilebase + lane*16B).

#define KT      64
#define NKT     7      // 7*64 = 448 >= 400 (pad zeroed)
#define MTILES  7      // 7*16 = 112 >= 100 rows
#define WPL     7168   // shorts: [mt 0..6][ks 0..1][lane 0..63][j 0..7]
#define XPL     1024   // shorts: [ks 0..1][lane 0..63][j 0..7] per batch-plane

__global__ __launch_bounds__(256) void gemm_kernel(const float* __restrict__ X,
                                                   const float* __restrict__ W,
                                                   float* __restrict__ Y) {
  __shared__ short lds[2 * WPL + 4 * 4 * XPL];  // whi, wlo, 4 waves * [b0h,b0l,b1h,b1l]
  short* whi = lds;
  short* wlo = lds + WPL;
  const int tid  = threadIdx.x;
  const int lane = tid & 63;
  const int wv   = __builtin_amdgcn_readfirstlane(tid >> 6);
  short* xp = lds + 2 * WPL + wv * (4 * XPL);
  const long b0 = (long)blockIdx.x * 8 + wv * 2;
  const long b1 = b0 + 1;

  f32x4 acc0[MTILES], acc1[MTILES];
  #pragma unroll
  for (int t = 0; t < MTILES; ++t) {
    acc0[t] = (f32x4){0.f, 0.f, 0.f, 0.f};
    acc1[t] = (f32x4){0.f, 0.f, 0.f, 0.f};
  }

  for (int kt = 0; kt < NKT; ++kt) {
    const int k0 = kt * KT;
    __syncthreads();  // WAR: previous tile's frag reads done before overwrite

    // ---- stage W tile (cooperative, 256 threads, 6400 floats) ----
    for (int i = tid * 4; i < D_OUT * KT; i += 1024) {
      const int o  = i >> 6;     // W row 0..99
      const int kk = i & 63;     // multiple of 4
      float w[4];
      if (k0 + kk + 3 < D_IN) {
        float4 v = *(const float4*)(W + o * D_IN + k0 + kk);
        w[0] = v.x; w[1] = v.y; w[2] = v.z; w[3] = v.w;
      } else {
        #pragma unroll
        for (int u = 0; u < 4; ++u)
          w[u] = (k0 + kk + u < D_IN) ? W[o * D_IN + k0 + kk + u] : 0.f;
      }
      const int ks = kk >> 5, quad = (kk & 31) >> 3, j = kk & 7;
      const int base = (((o >> 4) * 2 + ks) * 64 + quad * 16 + (o & 15)) * 8 + j;
      #pragma unroll
      for (int u = 0; u < 4; ++u) {
        __bf16 h = (__bf16)w[u];
        float hf = (float)h;
        __bf16 l = (__bf16)(w[u] - hf);
        whi[base + u] = __builtin_bit_cast(short, h);
        wlo[base + u] = __builtin_bit_cast(short, l);
      }
    }

    // ---- stage X tiles for this wave's 2 batches (frag order, hi/lo) ----
    {
      const int k  = k0 + lane;
      const bool ok = (k < D_IN);
      const int ks = lane >> 5, quad = (lane & 31) >> 3, j = lane & 7;
      const int wbase = (ks * 64 + quad * 16) * 8 + j;
      const float* xr0 = X + b0 * (long)(D_IN * QD) + (long)k * QD;
      const float* xr1 = X + b1 * (long)(D_IN * QD) + (long)k * QD;
      #pragma unroll
      for (int n = 0; n < QD; ++n) {
        float x = ok ? xr0[n] : 0.f;
        __bf16 h = (__bf16)x; float hf = (float)h; __bf16 l = (__bf16)(x - hf);
        xp[0 * XPL + wbase + n * 8] = __builtin_bit_cast(short, h);
        xp[1 * XPL + wbase + n * 8] = __builtin_bit_cast(short, l);
      }
      #pragma unroll
      for (int n = 0; n < QD; ++n) {
        float x = ok ? xr1[n] : 0.f;
        __bf16 h = (__bf16)x; float hf = (float)h; __bf16 l = (__bf16)(x - hf);
        xp[2 * XPL + wbase + n * 8] = __builtin_bit_cast(short, h);
        xp[3 * XPL + wbase + n * 8] = __builtin_bit_cast(short, l);
      }
    }
    __syncthreads();

    // ---- MFMA: 2 k-steps x 7 m-tiles x (3 split-products x 2 batches) ----
    #pragma unroll
    for (int ks = 0; ks < 2; ++ks) {
      const int fl = (ks * 64 + lane) * 8;
      bf16x8 b0h = *(const bf16x8*)&xp[0 * XPL + fl];
      bf16x8 b0l = *(const bf16x8*)&xp[1 * XPL + fl];
      bf16x8 b1h = *(const bf16x8*)&xp[2 * XPL + fl];
      bf16x8 b1l = *(const bf16x8*)&xp[3 * XPL + fl];
      #pragma unroll
      for (int mt = 0; mt < MTILES; ++mt) {
        const int al = ((mt * 2 + ks) * 64 + lane) * 8;
        bf16x8 ah  = *(const bf16x8*)&whi[al];
        bf16x8 alo = *(const bf16x8*)&wlo[al];
        acc0[mt] = __builtin_amdgcn_mfma_f32_16x16x32_bf16(ah,  b0h, acc0[mt], 0, 0, 0);
        acc0[mt] = __builtin_amdgcn_mfma_f32_16x16x32_bf16(alo, b0h, acc0[mt], 0, 0, 0);
        acc0[mt] = __builtin_amdgcn_mfma_f32_16x16x32_bf16(ah,  b0l, acc0[mt], 0, 0, 0);
        acc1[mt] = __builtin_amdgcn_mfma_f32_16x16x32_bf16(ah,  b1h, acc1[mt], 0, 0, 0);
        acc1[mt] = __builtin_amdgcn_mfma_f32_16x16x32_bf16(alo, b1h, acc1[mt], 0, 0, 0);
        acc1[mt] = __builtin_amdgcn_mfma_f32_16x16x32_bf16(ah,  b1l, acc1[mt], 0, 0, 0);
      }
    }
  }

  // ---- epilogue: C layout col=lane&15, row=quad*4+reg  ->  Y (b,100,10) ----
  const int col = lane & 15, quad = lane >> 4;
  if (col < QD) {
    float* y0p = Y + b0 * (long)(D_OUT * QD);
    float* y1p = Y + b1 * (long)(D_OUT * QD);
    #pragma unroll
    for (int mt = 0; mt < MTILES; ++mt)
      #pragma unroll
      for (int rr = 0; rr < 4; ++rr) {
        const int o = mt * 16 + quad * 4 + rr;
        if (o < D_OUT) {
          y0p[o * QD + col] = acc0[mt][rr];
          y1p[o * QD + col] = acc1[mt][rr];
        }
      }
  }
}

// ===================== Kernel B: per-wave Householder QR (round-1, proven) ======

__device__ __forceinline__ float wsum64(float x) {
  #pragma unroll
  for (int m = 1; m < 64; m <<= 1) x += __shfl_xor(x, m, 64);
  return x;
}

__global__ __launch_bounds__(256) void qr_kernel(const float* __restrict__ Yin,
                                                 float* __restrict__ out) {
  __shared__ float smem[4 * D_OUT * QD];
  const int tid = threadIdx.x;
  const int r   = tid & 63;
  const int wv  = __builtin_amdgcn_readfirstlane(tid >> 6);
  const long b  = (long)blockIdx.x * 4 + wv;
  const float* yb = Yin + b * (long)(D_OUT * QD);

  // lane r owns rows r and r+64 of the zero-padded 128-row panel
  float acc0[QD], acc1[QD];
  #pragma unroll
  for (int q = 0; q < QD; ++q) acc0[q] = yb[r * QD + q];
  const bool has1 = (r + 64) < D_OUT;
  #pragma unroll
  for (int q = 0; q < QD; ++q) acc1[q] = has1 ? yb[(r + 64) * QD + q] : 0.f;

  // ---- Householder QR, LAPACK sgeqrf convention ----
  float v0[QD], v1[QD], tau[QD];
  #pragma unroll
  for (int j = 0; j < QD; ++j) {
    float cj0  = (r >= j) ? acc0[j] : 0.f;
    float part = cj0 * cj0 + acc1[j] * acc1[j];
    float sig  = wsum64(part);
    float alpha = __shfl(acc0[j], j, 64);
    float nrm  = sqrtf(sig);
    float beta = (alpha >= 0.f) ? -nrm : nrm;
    float tj   = (nrm > 0.f) ? (beta - alpha) / beta : 0.f;
    float inv  = (nrm > 0.f) ? 1.f / (alpha - beta) : 0.f;
    tau[j] = tj;
    v0[j]  = (r == j) ? 1.f : ((r > j) ? acc0[j] * inv : 0.f);
    v1[j]  = acc1[j] * inv;
    #pragma unroll
    for (int k = j + 1; k < QD; ++k) {
      float p = v0[j] * acc0[k] + v1[j] * acc1[k];
      float s = wsum64(p) * tj;
      acc0[k] -= s * v0[j];
      acc1[k] -= s * v1[j];
    }
  }

  // ---- Q = H_0 ... H_9 * E (backward accumulation) ----
  float q0[QD], q1[QD];
  #pragma unroll
  for (int c = 0; c < QD; ++c) { q0[c] = (r == c) ? 1.f : 0.f; q1[c] = 0.f; }
  #pragma unroll
  for (int j = QD - 1; j >= 0; --j) {
    #pragma unroll
    for (int c = j; c < QD; ++c) {
      float p = v0[j] * q0[c] + v1[j] * q1[c];
      float s = wsum64(p) * tau[j];
      q0[c] -= s * v0[j];
      q1[c] -= s * v1[j];
    }
  }

  // ---- stage in LDS, store coalesced float4 ----
  float* stg = smem + wv * (D_OUT * QD);
  #pragma unroll
  for (int c = 0; c < QD; ++c) stg[r * QD + c] = q0[c];
  if (has1) {
    #pragma unroll
    for (int c = 0; c < QD; ++c) stg[(r + 64) * QD + c] = q1[c];
  }
  const float4* src = (const float4*)stg;
  float4* dst = (float4*)(out + b * (long)(D_OUT * QD));
  #pragma unroll
  for (int u = r; u < (D_OUT * QD) / 4; u += 64) dst[u] = src[u];
}

extern "C" void kernel_launch(void* const* d_in, const int* in_sizes, int n_in,
                              void* d_out, int out_size, void* d_ws, size_t ws_size,
                              hipStream_t stream) {
  const float* X = (const float*)d_in[0];   // (8192, 400, 10) fp32
  const float* W = (const float*)d_in[1];   // (100, 400) fp32
  float* out = (float*)d_out;               // (8192, 100, 10) fp32
  float* Yws = (float*)d_ws;                // 8192*1000 floats = 32.77 MB scratch
  hipLaunchKernelGGL(gemm_kernel, dim3(BATCHES / 8), dim3(256), 0, stream, X, W, Yws);
  hipLaunchKernelGGL(qr_kernel,   dim3(BATCHES / 4), dim3(256), 0, stream, Yws, out);
}

// Round 3
// 295.983 us; speedup vs baseline: 1.3090x; 1.0945x over previous
//
#include <hip/hip_runtime.h>
#include <math.h>

#define BATCHES 8192
#define D_IN    400
#define D_OUT   100
#define QD      10
#define KT      64
#define NKT     7                              // 7*64 = 448 >= 400
#define MTILES  7                              // 7*16 = 112 >= 100
#define WFSZ    (NKT * MTILES * 2 * 64 * 8)    // 50176 shorts per plane
#define XB      648                            // floats per batch region (640 + 8 pad)
#define NW      4                              // waves per block

using bf16x8 = __attribute__((ext_vector_type(8))) short;
using f32x4  = __attribute__((ext_vector_type(4))) float;

__device__ __forceinline__ float wsum64(float x) {
  #pragma unroll
  for (int m = 1; m < 64; m <<= 1) x += __shfl_xor(x, m, 64);
  return x;
}

// ---------- prep: W (100,400) fp32 -> A-fragment-ordered bf16 hi/lo planes ----
// layout: e = (((kt*7+mt)*2+ks)*64 + lane)*8 + j ; lane = quad*16 + row16
// padded entries (o>=100 or k>=400) written as ZERO (k-pad must be finite).
__global__ __launch_bounds__(256) void wprep_kernel(const float* __restrict__ W,
                                                    short* __restrict__ wfh,
                                                    short* __restrict__ wfl) {
  const int e = blockIdx.x * 256 + threadIdx.x;
  if (e >= WFSZ) return;
  const int j = e & 7, lane = (e >> 3) & 63, ks = (e >> 9) & 1, mtkt = e >> 10;
  const int kt = mtkt / MTILES, mt = mtkt - kt * MTILES;
  const int o = mt * 16 + (lane & 15);
  const int k = kt * KT + ks * 32 + (lane >> 4) * 8 + j;
  const float w = (o < D_OUT && k < D_IN) ? W[o * D_IN + k] : 0.f;
  __bf16 h = (__bf16)w;
  float hf = (float)h;
  __bf16 l = (__bf16)(w - hf);
  wfh[e] = __builtin_bit_cast(short, h);
  wfl[e] = __builtin_bit_cast(short, l);
}

// ---------- fused: Y = W@X[b] (MFMA, bf16 3-split) then Householder QR -------

// Round-1-proven QR (LAPACK sgeqrf convention) + staging glue. stg holds the
// 100x10 panel (row-major); dst is out + b*1000. All wave-private, no barriers.
__device__ __forceinline__ void qr_and_store(const f32x4* acc, float* stg,
                                             float* dst, int lane, int col,
                                             int quad) {
  // C-layout (col=lane&15, row=quad*4+rr) -> row-major panel in LDS
  if (col < QD) {
    #pragma unroll
    for (int mt = 0; mt < MTILES; ++mt)
      #pragma unroll
      for (int rr = 0; rr < 4; ++rr) {
        const int o = mt * 16 + quad * 4 + rr;
        if (o < D_OUT) stg[o * QD + col] = acc[mt][rr];
      }
  }
  // lane r owns rows r and r+64 of the zero-padded 128-row panel
  const int r = lane;
  float a0[QD], a1[QD];
  #pragma unroll
  for (int q = 0; q < QD; ++q) a0[q] = stg[r * QD + q];
  const bool has1 = (r + 64) < D_OUT;
  #pragma unroll
  for (int q = 0; q < QD; ++q) a1[q] = has1 ? stg[(r + 64) * QD + q] : 0.f;

  float v0[QD], v1[QD], tau[QD];
  #pragma unroll
  for (int j = 0; j < QD; ++j) {
    float cj0  = (r >= j) ? a0[j] : 0.f;
    float part = cj0 * cj0 + a1[j] * a1[j];
    float sig  = wsum64(part);
    float alpha = __shfl(a0[j], j, 64);
    float nrm  = sqrtf(sig);
    float beta = (alpha >= 0.f) ? -nrm : nrm;
    float tj   = (nrm > 0.f) ? (beta - alpha) / beta : 0.f;
    float inv  = (nrm > 0.f) ? 1.f / (alpha - beta) : 0.f;
    tau[j] = tj;
    v0[j]  = (r == j) ? 1.f : ((r > j) ? a0[j] * inv : 0.f);
    v1[j]  = a1[j] * inv;
    #pragma unroll
    for (int k = j + 1; k < QD; ++k) {
      float p = v0[j] * a0[k] + v1[j] * a1[k];
      float s = wsum64(p) * tj;
      a0[k] -= s * v0[j];
      a1[k] -= s * v1[j];
    }
  }
  float q0[QD], q1[QD];
  #pragma unroll
  for (int c = 0; c < QD; ++c) { q0[c] = (r == c) ? 1.f : 0.f; q1[c] = 0.f; }
  #pragma unroll
  for (int j = QD - 1; j >= 0; --j) {
    #pragma unroll
    for (int c = j; c < QD; ++c) {
      float p = v0[j] * q0[c] + v1[j] * q1[c];
      float s = wsum64(p) * tau[j];
      q0[c] -= s * v0[j];
      q1[c] -= s * v1[j];
    }
  }
  // Q back to LDS, then coalesced float4 store
  #pragma unroll
  for (int c = 0; c < QD; ++c) stg[r * QD + c] = q0[c];
  if (has1) {
    #pragma unroll
    for (int c = 0; c < QD; ++c) stg[(r + 64) * QD + c] = q1[c];
  }
  const float4* src = (const float4*)stg;
  float4* d4 = (float4*)dst;
  #pragma unroll
  for (int u = r; u < (D_OUT * QD) / 4; u += 64) d4[u] = src[u];
}

__global__ __launch_bounds__(256, 3) void fused_kernel(const float* __restrict__ X,
                                                       const short* __restrict__ wfh,
                                                       const short* __restrict__ wfl,
                                                       float* __restrict__ out) {
  __shared__ float xstg[NW * 2 * XB];   // wave-private fp32 X tiles / QR staging
  const int tid  = threadIdx.x;
  const int lane = tid & 63;
  const int wv   = __builtin_amdgcn_readfirstlane(tid >> 6);
  const long b0  = (long)blockIdx.x * (NW * 2) + wv * 2;
  float* xs = xstg + wv * (2 * XB);
  const int col = lane & 15, quad = lane >> 4;

  f32x4 acc0[MTILES], acc1[MTILES];
  #pragma unroll
  for (int t = 0; t < MTILES; ++t) {
    acc0[t] = (f32x4){0.f, 0.f, 0.f, 0.f};
    acc1[t] = (f32x4){0.f, 0.f, 0.f, 0.f};
  }

  // register prefetch of tile 0 (all 640 floats/batch valid at kt=0)
  float4 pre[5];
  #pragma unroll
  for (int u = 0; u < 5; ++u) {
    const int idx = lane + u * 64;          // 0..319 over [b0 tile | b1 tile]
    const int bsel = idx >= 160 ? 1 : 0;
    const int within = idx - bsel * 160;    // float4 index in tile
    pre[u] = *(const float4*)(X + (b0 + bsel) * (long)(D_IN * QD) + within * 4);
  }

  #pragma unroll 1
  for (int kt = 0; kt < NKT; ++kt) {
    const int k0 = kt * KT;
    // ---- commit prefetched tile to this wave's LDS region ----
    #pragma unroll
    for (int u = 0; u < 5; ++u) {
      const int idx = lane + u * 64;
      const int bsel = idx >= 160 ? 1 : 0;
      const int within = idx - bsel * 160;
      *(float4*)&xs[bsel * XB + within * 4] = pre[u];
    }
    // ---- register-prefetch next tile (zero-fill past k=400) ----
    if (kt + 1 < NKT) {
      const int nk0 = k0 + KT;
      const int vf4 = (nk0 + KT <= D_IN) ? 160 : ((D_IN - nk0) * QD) / 4;  // 160 | 40
      #pragma unroll
      for (int u = 0; u < 5; ++u) {
        const int idx = lane + u * 64;
        const int bsel = idx >= 160 ? 1 : 0;
        const int within = idx - bsel * 160;
        float4 v = {0.f, 0.f, 0.f, 0.f};
        if (within < vf4)
          v = *(const float4*)(X + (b0 + bsel) * (long)(D_IN * QD) + nk0 * QD + within * 4);
        pre[u] = v;
      }
    }
    // ---- MFMA over this tile; A-frags straight from global (L1/L2-resident) --
    const short* wh_kt = wfh + (long)kt * (MTILES * 2 * 64 * 8);
    const short* wl_kt = wfl + (long)kt * (MTILES * 2 * 64 * 8);
    #pragma unroll
    for (int ks = 0; ks < 2; ++ks) {
      // B-frag gather from fp32 LDS (2-way banks = free) + in-register split.
      // cols 10..15 read neighboring rows -> garbage only in unread acc cols.
      bf16x8 b0h, b0l, b1h, b1l;
      #pragma unroll
      for (int m = 0; m < 8; ++m) {
        const int fo = (ks * 32 + quad * 8 + m) * QD + col;
        float x0 = xs[fo];
        float x1 = xs[XB + fo];
        __bf16 h0 = (__bf16)x0; float f0 = (float)h0; __bf16 g0 = (__bf16)(x0 - f0);
        __bf16 h1 = (__bf16)x1; float f1 = (float)h1; __bf16 g1 = (__bf16)(x1 - f1);
        b0h[m] = __builtin_bit_cast(short, h0); b0l[m] = __builtin_bit_cast(short, g0);
        b1h[m] = __builtin_bit_cast(short, h1); b1l[m] = __builtin_bit_cast(short, g1);
      }
      #pragma unroll
      for (int mt = 0; mt < MTILES; ++mt) {
        const int ao = ((mt * 2 + ks) * 64 + lane) * 8;
        bf16x8 ah = *(const bf16x8*)(wh_kt + ao);
        bf16x8 al = *(const bf16x8*)(wl_kt + ao);
        acc0[mt] = __builtin_amdgcn_mfma_f32_16x16x32_bf16(ah, b0h, acc0[mt], 0, 0, 0);
        acc0[mt] = __builtin_amdgcn_mfma_f32_16x16x32_bf16(al, b0h, acc0[mt], 0, 0, 0);
        acc0[mt] = __builtin_amdgcn_mfma_f32_16x16x32_bf16(ah, b0l, acc0[mt], 0, 0, 0);
        acc1[mt] = __builtin_amdgcn_mfma_f32_16x16x32_bf16(ah, b1h, acc1[mt], 0, 0, 0);
        acc1[mt] = __builtin_amdgcn_mfma_f32_16x16x32_bf16(al, b1h, acc1[mt], 0, 0, 0);
        acc1[mt] = __builtin_amdgcn_mfma_f32_16x16x32_bf16(ah, b1l, acc1[mt], 0, 0, 0);
      }
    }
  }

  // ---- fused QR + store, one batch at a time (stg reuses the X region) ----
  qr_and_store(acc0, xs, out + b0 * (long)(D_OUT * QD), lane, col, quad);
  qr_and_store(acc1, xs, out + (b0 + 1) * (long)(D_OUT * QD), lane, col, quad);
}

extern "C" void kernel_launch(void* const* d_in, const int* in_sizes, int n_in,
                              void* d_out, int out_size, void* d_ws, size_t ws_size,
                              hipStream_t stream) {
  const float* X = (const float*)d_in[0];   // (8192, 400, 10) fp32
  const float* W = (const float*)d_in[1];   // (100, 400) fp32
  float* out = (float*)d_out;               // (8192, 100, 10) fp32
  short* wfh = (short*)d_ws;                // 50176 shorts
  short* wfl = wfh + WFSZ;                  // 50176 shorts (offset 100352 B, 16-aligned)
  hipLaunchKernelGGL(wprep_kernel, dim3((WFSZ + 255) / 256), dim3(256), 0, stream,
                     W, wfh, wfl);
  hipLaunchKernelGGL(fused_kernel, dim3(BATCHES / (NW * 2)), dim3(256), 0, stream,
                     X, wfh, wfl, out);
}